// Round 1
// baseline (86.725 us; speedup 1.0000x reference)
//
#include <hip/hip_runtime.h>
#include <stdint.h>

// Problem constants (fixed by reference): z (32,64,32,32) fp32, codebook (1024,64) fp32
#define NUM_E     1024
#define DIM       64
#define NPOS      32768      // 32*32*32 spatial positions
#define OUT_ELEMS 2097152    // 32*64*32*32

typedef short  short8  __attribute__((ext_vector_type(8)));   // 8 bf16 = 4 VGPRs (guide-verified operand type)
typedef float  f32x4   __attribute__((ext_vector_type(4)));

__device__ __forceinline__ unsigned short f32_to_bf16(float f) {
    uint32_t u = __builtin_bit_cast(uint32_t, f);
    u += 0x8000u;                       // round-half-up; plenty accurate here
    return (unsigned short)(u >> 16);
}

// ---------------- prep: bf16 codebook + (-0.5*||c||^2) + zero loss slot ----------------
__global__ __launch_bounds__(256) void vq_prep(const float* __restrict__ cb,
                                               unsigned short* __restrict__ cbb,
                                               float* __restrict__ g0,
                                               float* __restrict__ loss_out) {
    int k = blockIdx.x * 256 + threadIdx.x;   // 0..1023 (grid 4x256)
    if (k == 0) loss_out[0] = 0.0f;           // d_out is poisoned 0xAA before every launch
    if (k >= NUM_E) return;
    const float* row = cb + k * DIM;
    float s = 0.0f;
    uint32_t packed[DIM / 2];
#pragma unroll
    for (int c = 0; c < DIM; c += 2) {
        float a = row[c], b = row[c + 1];
        s += a * a + b * b;
        packed[c >> 1] = (uint32_t)f32_to_bf16(a) | ((uint32_t)f32_to_bf16(b) << 16);
    }
    g0[k] = -0.5f * s;
    uint4* dst = (uint4*)(cbb + k * DIM);     // 128B rows, 16B aligned
#pragma unroll
    for (int q = 0; q < 8; ++q)
        dst[q] = make_uint4(packed[q * 4], packed[q * 4 + 1], packed[q * 4 + 2], packed[q * 4 + 3]);
}

// ---------------- main: fused distances (MFMA) + argmin + gather + loss ----------------
// Block: 256 threads (4 waves) handles 64 consecutive positions.
// Wave w scans entries [256w, 256w+256). 512 blocks -> 2048 waves (2/SIMD).
__global__ __launch_bounds__(256, 2) void vq_main(
    const float* __restrict__ z,
    const float* __restrict__ cb,            // fp32 codebook (exact gather)
    const unsigned short* __restrict__ cbb,  // bf16 codebook
    const float* __restrict__ g0,            // -0.5*||c_k||^2
    float* __restrict__ out,
    float* __restrict__ loss_out)
{
    const int tid  = threadIdx.x;
    const int lane = tid & 63;
    const int w    = __builtin_amdgcn_readfirstlane(tid >> 6);  // 0..3, wave-uniform
    const int quad = lane >> 4;
    const int r16  = lane & 15;

    const int n0    = blockIdx.x * 64;           // first position of this block
    const int b     = n0 >> 10;                  // batch (tiles never cross batches: 64 | 1024)
    const int zbase = b * 65536 + (n0 & 1023);   // float index of (b, c=0, hw0)

    // ---- A fragments: 4 pos-tiles x 2 K-halves. A[m=lane&15][k=quad*8+j] (m120-verified)
    short8 afrag[4][2];
#pragma unroll
    for (int pt = 0; pt < 4; ++pt) {
        const int n_off = pt * 16 + r16;
#pragma unroll
        for (int half = 0; half < 2; ++half) {
            const int cbase = quad * 8 + half * 32;
            short8 f;
#pragma unroll
            for (int j = 0; j < 8; ++j)
                f[j] = (short)f32_to_bf16(z[zbase + (cbase + j) * 1024 + n_off]);
            afrag[pt][half] = f;
        }
    }

    // ---- scan this wave's 256-entry quarter in 16-entry tiles
    const int e0 = w * 256;
    float best[4][4];
    int   bidx[4][4];
#pragma unroll
    for (int pt = 0; pt < 4; ++pt)
#pragma unroll
        for (int r = 0; r < 4; ++r) { best[pt][r] = -1e30f; bidx[pt][r] = 0; }

    for (int it = 0; it < 16; ++it) {
        const int ecol = e0 + it * 16 + r16;           // this lane's column entry
        const float nh = g0[ecol];
        f32x4 cvec = {nh, nh, nh, nh};                 // fold -0.5||c||^2 into accumulator init
        // B[k=quad*8+j][n=lane&15] for C = A*B with B = codebook^T  => read codebook rows
        const short8 bf0 = *reinterpret_cast<const short8*>(cbb + ecol * 64 + quad * 8);
        const short8 bf1 = *reinterpret_cast<const short8*>(cbb + ecol * 64 + quad * 8 + 32);
#pragma unroll
        for (int pt = 0; pt < 4; ++pt) {
            f32x4 acc = __builtin_amdgcn_mfma_f32_16x16x32_bf16(afrag[pt][0], bf0, cvec, 0, 0, 0);
            acc = __builtin_amdgcn_mfma_f32_16x16x32_bf16(afrag[pt][1], bf1, acc, 0, 0, 0);
            // C/D layout: col = lane&15 (== ecol's r16), row = quad*4 + r  (m89-verified)
#pragma unroll
            for (int r = 0; r < 4; ++r) {
                if (acc[r] > best[pt][r]) { best[pt][r] = acc[r]; bidx[pt][r] = ecol; }
            }
        }
    }

    // ---- cross-lane argmax within each quad (16 lanes hold 16 column-classes of same rows)
    // key = monotone(g) upper 22 bits | (1023 - idx)  -> max picks max g, ties -> smaller idx
    __shared__ unsigned int cand[4][64];
    __shared__ float lsum[4];
#pragma unroll
    for (int pt = 0; pt < 4; ++pt) {
#pragma unroll
        for (int r = 0; r < 4; ++r) {
            unsigned int u  = __builtin_bit_cast(unsigned int, best[pt][r]);
            unsigned int mk = u ^ (((unsigned int)((int)u >> 31)) | 0x80000000u);
            unsigned int key = (mk & 0xFFFFFC00u) | (unsigned int)(1023 - bidx[pt][r]);
#pragma unroll
            for (int d = 1; d < 16; d <<= 1) {
                unsigned int o = __shfl_xor(key, d, 64);
                key = (o > key) ? o : key;
            }
            if (r16 == 0) cand[w][pt * 16 + quad * 4 + r] = key;
        }
    }
    __syncthreads();

    // ---- combine the 4 wave-quarters; every thread resolves row = lane's winner
    unsigned int k0 = cand[0][lane], k1 = cand[1][lane];
    unsigned int k2 = cand[2][lane], k3 = cand[3][lane];
    unsigned int fk = k0 > k1 ? k0 : k1;
    unsigned int fk2 = k2 > k3 ? k2 : k3;
    fk = fk > fk2 ? fk : fk2;
    const int widx = 1023 - (int)(fk & 1023u);

    // ---- gather exact fp32 codebook row, write zq (same layout as z), fused loss
    float ls = 0.0f;
#pragma unroll
    for (int i4 = 0; i4 < 4; ++i4) {
        const int c = w * 16 + i4 * 4;
        const float4 cv = *reinterpret_cast<const float4*>(cb + widx * 64 + c);
        const float q4[4] = {cv.x, cv.y, cv.z, cv.w};
#pragma unroll
        for (int j = 0; j < 4; ++j) {
            const int off = zbase + (c + j) * 1024 + lane;   // lane <-> position n0+lane
            const float zv = z[off];
            out[off] = q4[j];
            const float d = q4[j] - zv;
            ls += d * d;
        }
    }
    // wave reduce, then one atomic per block
#pragma unroll
    for (int d = 1; d < 64; d <<= 1) ls += __shfl_xor(ls, d, 64);
    if (lane == 0) lsum[w] = ls;
    __syncthreads();
    if (tid == 0) {
        const float t = (lsum[0] + lsum[1] + lsum[2] + lsum[3]) * (1.25f / (float)OUT_ELEMS);
        atomicAdd(loss_out, t);
    }
}

extern "C" void kernel_launch(void* const* d_in, const int* in_sizes, int n_in,
                              void* d_out, int out_size, void* d_ws, size_t ws_size,
                              hipStream_t stream) {
    const float* z  = (const float*)d_in[0];   // (32,64,32,32) fp32
    const float* cb = (const float*)d_in[1];   // (1024,64) fp32
    unsigned short* cbb = (unsigned short*)d_ws;                       // 128 KB bf16 codebook
    float* g0   = (float*)((char*)d_ws + NUM_E * DIM * sizeof(unsigned short)); // 4 KB norms
    float* out  = (float*)d_out;               // zq (2097152) then loss (1)
    float* loss = out + OUT_ELEMS;

    vq_prep<<<4, 256, 0, stream>>>(cb, cbb, g0, loss);
    vq_main<<<NPOS / 64, 256, 0, stream>>>(z, cb, cbb, g0, out, loss);
}

// Round 2
// 83.267 us; speedup vs baseline: 1.0415x; 1.0415x over previous
//
#include <hip/hip_runtime.h>
#include <stdint.h>

// Problem constants: z (32,64,32,32) fp32, codebook (1024,64) fp32
#define NUM_E     1024
#define DIM       64
#define NPOS      32768      // 32*32*32 spatial positions
#define OUT_ELEMS 2097152    // 32*64*32*32

typedef short  short8  __attribute__((ext_vector_type(8)));   // 8 bf16 = 4 VGPRs
typedef float  f32x4   __attribute__((ext_vector_type(4)));

__device__ __forceinline__ unsigned int bf16r(float f) {
    uint32_t u = __builtin_bit_cast(uint32_t, f);
    return (u + 0x8000u) >> 16;            // round-half-up
}

// ---------------- prep: bf16 codebook + biased norm (1 - 0.5*||c||^2) ----------------
// 64 blocks x 256 threads; 16 lanes per codebook row (1024 rows total).
// float4 loads: each quad-group of 16 lanes reads one full 256B row contiguously.
__global__ __launch_bounds__(256) void vq_prep(const float* __restrict__ cb,
                                               unsigned short* __restrict__ cbb,
                                               float* __restrict__ g0b,
                                               float* __restrict__ loss_out) {
    const int tid  = threadIdx.x;
    const int lane = tid & 63;
    const int w    = tid >> 6;
    const int quad = lane >> 4, r16 = lane & 15;
    const int row  = blockIdx.x * 16 + w * 4 + quad;
    if (blockIdx.x == 0 && tid == 0) loss_out[0] = 0.0f;   // d_out poisoned 0xAA pre-launch

    const float4 v = *reinterpret_cast<const float4*>(cb + row * 64 + r16 * 4);
    float s = v.x * v.x + v.y * v.y + v.z * v.z + v.w * v.w;
#pragma unroll
    for (int d = 1; d < 16; d <<= 1) s += __shfl_xor(s, d, 64);  // sum within 16-lane row group
    if (r16 == 0) g0b[row] = 1.0f - 0.5f * s;   // +1 bias keeps all scores positive (see key trick)

    uint2 p;
    p.x = bf16r(v.x) | (bf16r(v.y) << 16);
    p.y = bf16r(v.z) | (bf16r(v.w) << 16);
    *reinterpret_cast<uint2*>(cbb + row * 64 + r16 * 4) = p;     // 128B contiguous per row group
}

// ---------------- main: fused distances (MFMA) + argmax-key + gather + loss ----------------
// Block: 256 threads (4 waves) handles 64 consecutive positions.
// Wave w scans entries [256w, 256w+256). 512 blocks -> 2 blocks/CU.
// Score g = z.c - 0.5||c||^2 + 1  (maximize <=> min distance; +1 => always positive float,
// so uint compare == float compare). Key = (g_bits & ~0x3FF) | (1023 - idx):
// v_max_u32 picks max g, ties -> smallest idx. Low-10-mantissa quantization (~1.2e-4)
// only flips near-ties; each flip bounded by codebook range (~2e-3) << 2.5e-2 threshold.
__global__ __launch_bounds__(256, 2) void vq_main(
    const float* __restrict__ z,
    const float* __restrict__ cb,            // fp32 codebook (exact gather)
    const unsigned short* __restrict__ cbb,  // bf16 codebook
    const float* __restrict__ g0b,           // 1 - 0.5*||c_k||^2
    float* __restrict__ out,
    float* __restrict__ loss_out)
{
    const int tid  = threadIdx.x;
    const int lane = tid & 63;
    const int w    = __builtin_amdgcn_readfirstlane(tid >> 6);  // 0..3, wave-uniform
    const int quad = lane >> 4;
    const int r16  = lane & 15;

    const int n0    = blockIdx.x * 64;           // first position of this block
    const int b     = n0 >> 10;                  // batch (64 | 1024: tiles never cross batches)
    const int zbase = b * 65536 + (n0 & 1023);   // float index of (b, c=0, hw0)

    // ---- A fragments: 4 pos-tiles x 2 K-halves. A[m=lane&15][k=quad*8+j]
    short8 afrag[4][2];
#pragma unroll
    for (int pt = 0; pt < 4; ++pt) {
        const int n_off = pt * 16 + r16;
#pragma unroll
        for (int half = 0; half < 2; ++half) {
            const int cbase = quad * 8 + half * 32;
            short8 f;
#pragma unroll
            for (int j = 0; j < 8; ++j)
                f[j] = (short)bf16r(z[zbase + (cbase + j) * 1024 + n_off]);
            afrag[pt][half] = f;
        }
    }

    // ---- scan this wave's 256-entry quarter in 16-entry tiles
    const int e0 = w * 256;
    unsigned int best[4][4];
#pragma unroll
    for (int pt = 0; pt < 4; ++pt)
#pragma unroll
        for (int r = 0; r < 4; ++r) best[pt][r] = 0u;

    for (int it = 0; it < 16; ++it) {
        const int ecol = e0 + it * 16 + r16;            // this lane's column entry
        const float nh = g0b[ecol];                     // biased: 1 - 0.5||c||^2
        const unsigned int idxenc = (unsigned int)(1023 - ecol);
        f32x4 cvec = {nh, nh, nh, nh};
        const short8 bf0 = *reinterpret_cast<const short8*>(cbb + ecol * 64 + quad * 8);
        const short8 bf1 = *reinterpret_cast<const short8*>(cbb + ecol * 64 + quad * 8 + 32);
#pragma unroll
        for (int pt = 0; pt < 4; ++pt) {
            f32x4 acc = __builtin_amdgcn_mfma_f32_16x16x32_bf16(afrag[pt][0], bf0, cvec, 0, 0, 0);
            acc = __builtin_amdgcn_mfma_f32_16x16x32_bf16(afrag[pt][1], bf1, acc, 0, 0, 0);
            // C/D layout: col = lane&15 (entry), row = quad*4 + r (position)
#pragma unroll
            for (int r = 0; r < 4; ++r) {
                unsigned int k = (__builtin_bit_cast(unsigned int, acc[r]) & 0xFFFFFC00u) | idxenc;
                best[pt][r] = best[pt][r] > k ? best[pt][r] : k;   // v_max_u32
            }
        }
    }

    // ---- cross-lane max within each 16-lane group (keys already carry the index)
    __shared__ unsigned int cand[4][64];
    __shared__ float lsum[4];
#pragma unroll
    for (int pt = 0; pt < 4; ++pt) {
#pragma unroll
        for (int r = 0; r < 4; ++r) {
            unsigned int key = best[pt][r];
#pragma unroll
            for (int d = 1; d < 16; d <<= 1) {
                unsigned int o = __shfl_xor(key, d, 64);
                key = (o > key) ? o : key;
            }
            if (r16 == 0) cand[w][pt * 16 + quad * 4 + r] = key;   // index = position in tile
        }
    }
    __syncthreads();

    // ---- combine the 4 wave-quarters; thread's lane picks position n0+lane's winner
    unsigned int k0 = cand[0][lane], k1 = cand[1][lane];
    unsigned int k2 = cand[2][lane], k3 = cand[3][lane];
    unsigned int fk  = k0 > k1 ? k0 : k1;
    unsigned int fk2 = k2 > k3 ? k2 : k3;
    fk = fk > fk2 ? fk : fk2;
    const int widx = 1023 - (int)(fk & 1023u);

    // ---- gather exact fp32 codebook row, write zq (same layout as z), fused loss
    float ls = 0.0f;
#pragma unroll
    for (int i4 = 0; i4 < 4; ++i4) {
        const int c = w * 16 + i4 * 4;
        const float4 cv = *reinterpret_cast<const float4*>(cb + widx * 64 + c);
        const float q4[4] = {cv.x, cv.y, cv.z, cv.w};
#pragma unroll
        for (int j = 0; j < 4; ++j) {
            const int off = zbase + (c + j) * 1024 + lane;   // lane <-> position n0+lane
            const float zv = z[off];
            out[off] = q4[j];
            const float d = q4[j] - zv;
            ls += d * d;
        }
    }
    // wave reduce, then one atomic per block
#pragma unroll
    for (int d = 1; d < 64; d <<= 1) ls += __shfl_xor(ls, d, 64);
    if (lane == 0) lsum[w] = ls;
    __syncthreads();
    if (tid == 0) {
        const float t = (lsum[0] + lsum[1] + lsum[2] + lsum[3]) * (1.25f / (float)OUT_ELEMS);
        atomicAdd(loss_out, t);
    }
}

extern "C" void kernel_launch(void* const* d_in, const int* in_sizes, int n_in,
                              void* d_out, int out_size, void* d_ws, size_t ws_size,
                              hipStream_t stream) {
    const float* z  = (const float*)d_in[0];   // (32,64,32,32) fp32
    const float* cb = (const float*)d_in[1];   // (1024,64) fp32
    unsigned short* cbb = (unsigned short*)d_ws;                       // 128 KB bf16 codebook
    float* g0b  = (float*)((char*)d_ws + NUM_E * DIM * sizeof(unsigned short)); // 4 KB biased norms
    float* out  = (float*)d_out;               // zq (2097152) then loss (1)
    float* loss = out + OUT_ELEMS;

    vq_prep<<<NUM_E / 16, 256, 0, stream>>>(cb, cbb, g0b, loss);
    vq_main<<<NPOS / 64, 256, 0, stream>>>(z, cb, cbb, g0b, out, loss);
}

// Round 3
// 82.269 us; speedup vs baseline: 1.0542x; 1.0121x over previous
//
#include <hip/hip_runtime.h>
#include <stdint.h>

// Problem constants: z (32,64,32,32) fp32, codebook (1024,64) fp32
#define NUM_E     1024
#define DIM       64
#define NPOS      32768      // 32*32*32 spatial positions
#define OUT_ELEMS 2097152    // 32*64*32*32

typedef short  short8  __attribute__((ext_vector_type(8)));   // 8 bf16 = 4 VGPRs
typedef float  f32x4   __attribute__((ext_vector_type(4)));

__device__ __forceinline__ unsigned int bf16r(float f) {
    uint32_t u = __builtin_bit_cast(uint32_t, f);
    return (u + 0x8000u) >> 16;            // round-half-up
}
__device__ __forceinline__ unsigned int pack2(float a, float b) {
    return bf16r(a) | (bf16r(b) << 16);
}

// ---------------- prep: bf16 codebook + biased norm (1 - 0.5*||c||^2) ----------------
// 64 blocks x 256 threads; 16 lanes per codebook row; float4 coalesced loads.
__global__ __launch_bounds__(256) void vq_prep(const float* __restrict__ cb,
                                               unsigned short* __restrict__ cbb,
                                               float* __restrict__ g0b,
                                               float* __restrict__ loss_out) {
    const int tid  = threadIdx.x;
    const int lane = tid & 63;
    const int w    = tid >> 6;
    const int quad = lane >> 4, r16 = lane & 15;
    const int row  = blockIdx.x * 16 + w * 4 + quad;
    if (blockIdx.x == 0 && tid == 0) loss_out[0] = 0.0f;   // d_out poisoned 0xAA pre-launch

    const float4 v = *reinterpret_cast<const float4*>(cb + row * 64 + r16 * 4);
    float s = v.x * v.x + v.y * v.y + v.z * v.z + v.w * v.w;
#pragma unroll
    for (int d = 1; d < 16; d <<= 1) s += __shfl_xor(s, d, 64);  // sum within 16-lane row group
    if (r16 == 0) g0b[row] = 1.0f - 0.5f * s;   // +1 bias keeps scores positive (uint-key trick)

    uint2 p;
    p.x = pack2(v.x, v.y);
    p.y = pack2(v.z, v.w);
    *reinterpret_cast<uint2*>(cbb + row * 64 + r16 * 4) = p;
}

// ---------------- main: LDS-staged z + MFMA distances + argmax-key + gather + loss ----------------
// Block: 256 threads (4 waves) = 64 consecutive positions. Wave w scans entries [256w, 256w+256).
// Score g = z.c - 0.5||c||^2 + 1 (max <=> min dist; +1 => positive => uint cmp == float cmp).
// Key = (g_bits & ~0x3FF) | (1023-idx): one v_and_or_b32 + one v_max_u32 per element.
#define ZP 68   // LDS row stride (floats): 64 + 4 pad — 16B-aligned, breaks pow-2 bank aliasing
__global__ __launch_bounds__(256, 2) void vq_main(
    const float* __restrict__ z,
    const float* __restrict__ cb,            // fp32 codebook (exact gather)
    const unsigned short* __restrict__ cbb,  // bf16 codebook
    const float* __restrict__ g0b,           // 1 - 0.5*||c_k||^2
    float* __restrict__ out,
    float* __restrict__ loss_out)
{
    const int tid  = threadIdx.x;
    const int lane = tid & 63;
    const int w    = __builtin_amdgcn_readfirstlane(tid >> 6);  // 0..3, wave-uniform
    const int quad = lane >> 4;
    const int r16  = lane & 15;

    const int n0    = blockIdx.x * 64;           // first position of this block
    const int b     = n0 >> 10;                  // batch (64 | 1024: tiles never cross batches)
    const int zbase = b * 65536 + (n0 & 1023);   // float index of (b, c=0, hw0)

    __shared__ float zt[64][ZP];                 // [position][channel], exact fp32
    __shared__ unsigned int cand[4][64];
    __shared__ float lsum[4];

    // ---- stage block's 16KB z-tile: coalesced float4 global loads, transposed LDS writes
#pragma unroll
    for (int p = 0; p < 4; ++p) {
        const int cc = p * 16 + (tid >> 4);      // channel 0..63
        const int f4 = tid & 15;                 // position quad 0..15
        const float4 v = *reinterpret_cast<const float4*>(z + zbase + cc * 1024 + f4 * 4);
        zt[f4 * 4 + 0][cc] = v.x;
        zt[f4 * 4 + 1][cc] = v.y;
        zt[f4 * 4 + 2][cc] = v.z;
        zt[f4 * 4 + 3][cc] = v.w;
    }
    __syncthreads();

    // ---- A fragments from LDS: A[m=r16][k=quad*8+j], m-position = pt*16+r16
    short8 afrag[4][2];
#pragma unroll
    for (int pt = 0; pt < 4; ++pt) {
#pragma unroll
        for (int half = 0; half < 2; ++half) {
            const float* src = &zt[pt * 16 + r16][quad * 8 + half * 32];
            const float4 a0 = *reinterpret_cast<const float4*>(src);
            const float4 a1 = *reinterpret_cast<const float4*>(src + 4);
            union { short8 s; uint32_t u[4]; } fr;
            fr.u[0] = pack2(a0.x, a0.y);
            fr.u[1] = pack2(a0.z, a0.w);
            fr.u[2] = pack2(a1.x, a1.y);
            fr.u[3] = pack2(a1.z, a1.w);
            afrag[pt][half] = fr.s;
        }
    }

    // ---- scan this wave's 256-entry quarter in 16-entry tiles
    const int e0 = w * 256;
    unsigned int best[4][4];
#pragma unroll
    for (int pt = 0; pt < 4; ++pt)
#pragma unroll
        for (int r = 0; r < 4; ++r) best[pt][r] = 0u;

    for (int it = 0; it < 16; ++it) {
        const int ecol = e0 + it * 16 + r16;            // this lane's column entry
        const float nh = g0b[ecol];                     // biased: 1 - 0.5||c||^2
        const unsigned int idxenc = (unsigned int)(1023 - ecol);
        f32x4 cvec = {nh, nh, nh, nh};
        const short8 bf0 = *reinterpret_cast<const short8*>(cbb + ecol * 64 + quad * 8);
        const short8 bf1 = *reinterpret_cast<const short8*>(cbb + ecol * 64 + quad * 8 + 32);
#pragma unroll
        for (int pt = 0; pt < 4; ++pt) {
            f32x4 acc = __builtin_amdgcn_mfma_f32_16x16x32_bf16(afrag[pt][0], bf0, cvec, 0, 0, 0);
            acc = __builtin_amdgcn_mfma_f32_16x16x32_bf16(afrag[pt][1], bf1, acc, 0, 0, 0);
            // C/D layout: col = lane&15 (entry), row = quad*4 + r (position)
#pragma unroll
            for (int r = 0; r < 4; ++r) {
                unsigned int k = (__builtin_bit_cast(unsigned int, acc[r]) & 0xFFFFFC00u) | idxenc;
                best[pt][r] = best[pt][r] > k ? best[pt][r] : k;   // v_max_u32
            }
        }
    }

    // ---- cross-lane max within each 16-lane group (keys carry the index)
#pragma unroll
    for (int pt = 0; pt < 4; ++pt) {
#pragma unroll
        for (int r = 0; r < 4; ++r) {
            unsigned int key = best[pt][r];
#pragma unroll
            for (int d = 1; d < 16; d <<= 1) {
                unsigned int o = __shfl_xor(key, d, 64);
                key = (o > key) ? o : key;
            }
            if (r16 == 0) cand[w][pt * 16 + quad * 4 + r] = key;   // index = position in tile
        }
    }
    __syncthreads();

    // ---- combine the 4 wave-quarters; lane picks position n0+lane's winner
    unsigned int k0 = cand[0][lane], k1 = cand[1][lane];
    unsigned int k2 = cand[2][lane], k3 = cand[3][lane];
    unsigned int fk  = k0 > k1 ? k0 : k1;
    unsigned int fk2 = k2 > k3 ? k2 : k3;
    fk = fk > fk2 ? fk : fk2;
    const int widx = 1023 - (int)(fk & 1023u);

    // ---- gather exact fp32 codebook row; z from LDS (exact); coalesced out; fused loss
    float ls = 0.0f;
#pragma unroll
    for (int i4 = 0; i4 < 4; ++i4) {
        const int c = w * 16 + i4 * 4;
        const float4 cv = *reinterpret_cast<const float4*>(cb + widx * 64 + c);
        const float4 zl = *reinterpret_cast<const float4*>(&zt[lane][c]);
        const float q4[4] = {cv.x, cv.y, cv.z, cv.w};
        const float z4[4] = {zl.x, zl.y, zl.z, zl.w};
#pragma unroll
        for (int j = 0; j < 4; ++j) {
            out[zbase + (c + j) * 1024 + lane] = q4[j];   // lane <-> position n0+lane
            const float d = q4[j] - z4[j];
            ls += d * d;
        }
    }
    // wave reduce, then one atomic per block
#pragma unroll
    for (int d = 1; d < 64; d <<= 1) ls += __shfl_xor(ls, d, 64);
    if (lane == 0) lsum[w] = ls;
    __syncthreads();
    if (tid == 0) {
        const float t = (lsum[0] + lsum[1] + lsum[2] + lsum[3]) * (1.25f / (float)OUT_ELEMS);
        atomicAdd(loss_out, t);
    }
}

extern "C" void kernel_launch(void* const* d_in, const int* in_sizes, int n_in,
                              void* d_out, int out_size, void* d_ws, size_t ws_size,
                              hipStream_t stream) {
    const float* z  = (const float*)d_in[0];   // (32,64,32,32) fp32
    const float* cb = (const float*)d_in[1];   // (1024,64) fp32
    unsigned short* cbb = (unsigned short*)d_ws;                       // 128 KB bf16 codebook
    float* g0b  = (float*)((char*)d_ws + NUM_E * DIM * sizeof(unsigned short)); // 4 KB biased norms
    float* out  = (float*)d_out;               // zq (2097152) then loss (1)
    float* loss = out + OUT_ELEMS;

    vq_prep<<<NUM_E / 16, 256, 0, stream>>>(cb, cbb, g0b, loss);
    vq_main<<<NPOS / 64, 256, 0, stream>>>(z, cb, cbb, g0b, out, loss);
}